// Round 15
// baseline (131.029 us; speedup 1.0000x reference)
//
#include <hip/hip_runtime.h>
#include <hip/hip_fp16.h>

#define N_FIN 128
#define N_HID 16
#define N_OUT 12
#define NBLK  1024        // binning blocks (entries layout: block-major chunks)
#define BN    512         // nodes per bucket (dl = dst & 511, bucket = dst >> 9)
#define STCAP 3200        // binsort LDS capacity (chunk = 3125)
#define SCAP  17152       // build LDS capacity per bucket (avg 16327, +6.5 sigma)
#define ECAP  4096        // gather LDS esrc stage (64 nodes: mean 2048, +45 sigma)

// ---------- block-local counting sort of a chunk by bucket ----------
__global__ __launch_bounds__(256) void k_binsort(const int* __restrict__ src,
                                                 const int* __restrict__ dst,
                                                 unsigned* __restrict__ hist,
                                                 unsigned* __restrict__ lstart,
                                                 unsigned* __restrict__ bucket_tot,
                                                 unsigned* __restrict__ entries,
                                                 int E, int chunk, int NB) {
  __shared__ unsigned lh[256];
  __shared__ unsigned cur[256];
  __shared__ unsigned stage[STCAP];
  __shared__ unsigned srt[STCAP];
  __shared__ unsigned char bid[STCAP];
  int t = threadIdx.x, blk = blockIdx.x;
  lh[t] = 0u;
  __syncthreads();
  int clo = blk * chunk, chi = min(E, clo + chunk), n = chi - clo;
  for (int j = clo + t; j < chi; j += 256) {
    int d = dst[j], s = src[j];
    int b = d >> 9;
    stage[j - clo] = ((unsigned)s << 9) | (unsigned)(d & (BN - 1));
    bid[j - clo] = (unsigned char)b;
    atomicAdd(&lh[b], 1u);
  }
  __syncthreads();
  unsigned v = lh[t];
  cur[t] = v;
  __syncthreads();
#pragma unroll
  for (int off = 1; off < 256; off <<= 1) {
    unsigned y = (t >= off) ? cur[t - off] : 0u;
    __syncthreads();
    cur[t] += y;
    __syncthreads();
  }
  unsigned excl = cur[t] - v;
  if (t < NB) {
    hist[(size_t)t * NBLK + blk]   = v;     // fragment length
    lstart[(size_t)t * NBLK + blk] = excl;  // fragment offset within chunk
    if (v) atomicAdd(&bucket_tot[t], v);
  }
  cur[t] = excl;
  __syncthreads();
  for (int i = t; i < n; i += 256) {
    unsigned p = atomicAdd(&cur[bid[i]], 1u);
    srt[p] = stage[i];
  }
  __syncthreads();
  for (int i = t; i < n; i += 256) entries[clo + i] = srt[i];   // coalesced
}

// ---------- fallback binary search ----------
__device__ __forceinline__ int frag_search(const unsigned* cum, unsigned i) {
  int lo = 0, hi = 1024;
  while (hi - lo > 1) { int mid = (lo + hi) >> 1; if (cum[mid] <= i) lo = mid; else hi = mid; }
  return lo;
}

// ---------- per-bucket build: inline scans + LUT-accelerated fragment search ----------
__global__ __launch_bounds__(1024) void k_build(const unsigned* __restrict__ entries,
                                                const unsigned* __restrict__ hist,
                                                const unsigned* __restrict__ lstart,
                                                const unsigned* __restrict__ bucket_tot,
                                                uint2* __restrict__ rsd,
                                                float* __restrict__ dinv,
                                                unsigned* __restrict__ esrc,
                                                int N, int NB, int E, int chunk) {
  __shared__ unsigned cum[1025];
  __shared__ unsigned lst[1024];
  __shared__ unsigned lut[1024];
  __shared__ unsigned cnt[BN];
  __shared__ unsigned cur[BN];
  __shared__ unsigned raw[SCAP];
  __shared__ unsigned srt[SCAP];
  int t = threadIdx.x, b = blockIdx.x;
  // inline exclusive scan of bucket totals (NB <= 256) -> bstart
  if (t < 256) cur[t] = (t < NB) ? bucket_tot[t] : 0u;
  __syncthreads();
#pragma unroll
  for (int off = 1; off < 256; off <<= 1) {
    unsigned y = 0;
    if (t < 256 && t >= off) y = cur[t - off];
    __syncthreads();
    if (t < 256) cur[t] += y;
    __syncthreads();
  }
  unsigned bstart = (b == 0) ? 0u : cur[b - 1];
  __syncthreads();
  // within-bucket fragment scan (1024 fragments)
  unsigned hv = hist[(size_t)b * NBLK + t];
  lst[t] = lstart[(size_t)b * NBLK + t];
  cum[t] = hv;
  __syncthreads();
#pragma unroll
  for (int off = 1; off < 1024; off <<= 1) {
    unsigned y = (t >= off) ? cum[t - off] : 0u;
    __syncthreads();
    cum[t] += y;
    __syncthreads();
  }
  unsigned incl = cum[t];
  __syncthreads();
  cum[t] = incl - hv;
  if (t == 1023) cum[1024] = incl;
  if (t < BN) cnt[t] = 0u;
  __syncthreads();
  unsigned tot = cum[1024];
  bool fits = (tot <= SCAP);
  // build slot LUT: fragment t covers query slots [ceil(lo*1024/tot), ceil(hi*1024/tot))
  if (tot) {
    unsigned lo = cum[t], hi = cum[t + 1];
    if (hi > lo) {
      unsigned k0 = (unsigned)(((unsigned long long)lo * 1024ull + tot - 1) / tot);
      unsigned k1 = (unsigned)(((unsigned long long)hi * 1024ull + tot - 1) / tot);
      if (k1 > 1024u) k1 = 1024u;
      for (unsigned k = k0; k < k1; ++k) lut[k] = (unsigned)t;
    }
  }
  __syncthreads();
  float scale = tot ? (1024.0f / (float)tot) : 0.f;
  // pass A: coalesced fragment reads via LUT search, stage raw, histogram dl
  if (fits) {
    for (unsigned i = t; i < tot; i += 1024) {
      unsigned k = (unsigned)((float)i * scale);
      if (k > 1023u) k = 1023u;
      int f = (int)lut[k];
      while (cum[f] > i) --f;
      while (cum[f + 1] <= i) ++f;
      unsigned en = entries[(size_t)f * chunk + lst[f] + (i - cum[f])];
      raw[i] = en;
      atomicAdd(&cnt[en & (BN - 1)], 1u);
    }
  } else {
    for (unsigned i = t; i < tot; i += 1024) {
      int f = frag_search(cum, i);
      unsigned en = entries[(size_t)f * chunk + lst[f] + (i - cum[f])];
      atomicAdd(&cnt[en & (BN - 1)], 1u);
    }
  }
  __syncthreads();
  unsigned v = (t < BN) ? cnt[t] : 0u;
  if (t < BN) cur[t] = v;
  __syncthreads();
#pragma unroll
  for (int off = 1; off < BN; off <<= 1) {
    unsigned y = (t < BN && t >= off) ? cur[t - off] : 0u;
    __syncthreads();
    if (t < BN) cur[t] += y;
    __syncthreads();
  }
  if (t < BN) {
    unsigned excl = cur[t] - v;
    cur[t] = fits ? excl : (bstart + excl);
    int node = b * BN + t;
    if (node < N) {
      rsd[node] = make_uint2(bstart + excl, v);
      dinv[node] = rsqrtf((float)(v + 1u));
    }
  }
  __syncthreads();
  if (fits) {
    for (unsigned i = t; i < tot; i += 1024) {
      unsigned en = raw[i];
      unsigned p = atomicAdd(&cur[en & (BN - 1)], 1u);
      srt[p] = en >> 9;
    }
    __syncthreads();
    for (unsigned i = t; i < tot; i += 1024) esrc[bstart + i] = srt[i];
  } else {   // fallback (never for uniform data): global scatter
    for (unsigned i = t; i < tot; i += 1024) {
      int f = frag_search(cum, i);
      unsigned en = entries[(size_t)f * chunk + lst[f] + (i - cum[f])];
      unsigned p = atomicAdd(&cur[en & (BN - 1)], 1u);
      esrc[p] = en >> 9;
    }
  }
}

// ---------------- hs = fp16( dinv * (x @ W1) ), x:[N,128] W1:[128,16] ----------------
__global__ __launch_bounds__(256) void k_gemm1(const float* __restrict__ x,
                                               const float* __restrict__ W1,
                                               const float* __restrict__ dinv,
                                               __half* __restrict__ hs, int N) {
  __shared__ float xs[16][132];
  __shared__ float wT[16][132];
  int t = threadIdx.x;
#pragma unroll
  for (int i = 0; i < 8; ++i) {
    int idx = t + i * 256;
    int k = idx >> 4, c = idx & 15;
    wT[c][k] = W1[idx];
  }
  int row0 = blockIdx.x * 16;
#pragma unroll
  for (int i = 0; i < 2; ++i) {
    int idx = t + i * 256;
    int r = idx >> 5, c4 = idx & 31;
    float4 v = make_float4(0.f, 0.f, 0.f, 0.f);
    if (row0 + r < N) v = *(const float4*)(x + (size_t)(row0 + r) * N_FIN + c4 * 4);
    *(float4*)&xs[r][c4 * 4] = v;
  }
  __syncthreads();
  int col = t & 15, r = t >> 4;
  float acc = 0.f;
#pragma unroll
  for (int kc = 0; kc < 32; ++kc) {
    float4 xv = *(const float4*)&xs[r][kc * 4];
    float4 wv = *(const float4*)&wT[col][kc * 4];
    acc += xv.x * wv.x + xv.y * wv.y + xv.z * wv.z + xv.w * wv.w;
  }
  int row = row0 + r;
  if (row < N) hs[(size_t)row * N_HID + col] = __float2half(dinv[row] * acc);
}

__device__ __forceinline__ float4 h4f(uint2 v) {
  __half2 h0 = *(__half2*)&v.x, h1 = *(__half2*)&v.y;
  float2 f0 = __half22float2(h0), f1 = __half22float2(h1);
  return make_float4(f0.x, f0.y, f1.x, f1.y);
}
#define ACC(a, v) { float4 f = h4f(v); a.x += f.x; a.y += f.y; a.z += f.z; a.w += f.w; }

// ------ layer1: LDS-staged esrc + 16-deep CSR gather (4 lanes/node) ------
__global__ __launch_bounds__(256) void k_gagg1(const unsigned* __restrict__ esrc,
                                               const uint2* __restrict__ rsd,
                                               const uint2* __restrict__ hs,
                                               const float* __restrict__ dinv,
                                               const float* __restrict__ b1,
                                               const float* __restrict__ W2,
                                               __half* __restrict__ hs2, int N) {
  __shared__ unsigned les[ECAP];
  __shared__ float os[64][17];
  __shared__ float w2s[N_HID][N_OUT];
  __shared__ float b1s[N_HID];
  int t = threadIdx.x;
  if (t < N_HID * N_OUT) w2s[t / N_OUT][t % N_OUT] = W2[t];
  if (t < N_HID) b1s[t] = b1[t];
  int node0 = blockIdx.x * 64;
  int lastn = min(node0 + 63, N - 1);
  uint2 rd0 = rsd[node0];
  uint2 rdl = rsd[lastn];
  unsigned bs = rd0.x, cnt = rdl.x + rdl.y - bs;
  bool fits = (cnt <= ECAP);
  if (fits) for (unsigned i = t; i < cnt; i += 256) les[i] = esrc[bs + i];
  __syncthreads();
  int nl = t >> 2, c4 = t & 3;
  int node = node0 + nl;
  if (node < N) {
    uint2 rd = rsd[node];
    unsigned dn = rd.y;
    float4 a0 = make_float4(0.f, 0.f, 0.f, 0.f), a1 = a0, a2 = a0, a3 = a0;
    if (fits) {
      unsigned lo = rd.x - bs;
      unsigned j = 0;
      for (; j + 16 <= dn; j += 16) {
        unsigned e0 = les[lo + j],      e1 = les[lo + j + 1];
        unsigned e2 = les[lo + j + 2],  e3 = les[lo + j + 3];
        unsigned e4 = les[lo + j + 4],  e5 = les[lo + j + 5];
        unsigned e6 = les[lo + j + 6],  e7 = les[lo + j + 7];
        unsigned e8 = les[lo + j + 8],  e9 = les[lo + j + 9];
        unsigned ea = les[lo + j + 10], eb = les[lo + j + 11];
        unsigned ec = les[lo + j + 12], ed = les[lo + j + 13];
        unsigned ee = les[lo + j + 14], ef = les[lo + j + 15];
        uint2 v0 = hs[(size_t)e0 * 4 + c4], v1 = hs[(size_t)e1 * 4 + c4];
        uint2 v2 = hs[(size_t)e2 * 4 + c4], v3 = hs[(size_t)e3 * 4 + c4];
        uint2 v4 = hs[(size_t)e4 * 4 + c4], v5 = hs[(size_t)e5 * 4 + c4];
        uint2 v6 = hs[(size_t)e6 * 4 + c4], v7 = hs[(size_t)e7 * 4 + c4];
        uint2 v8 = hs[(size_t)e8 * 4 + c4], v9 = hs[(size_t)e9 * 4 + c4];
        uint2 va = hs[(size_t)ea * 4 + c4], vb = hs[(size_t)eb * 4 + c4];
        uint2 vc = hs[(size_t)ec * 4 + c4], vd = hs[(size_t)ed * 4 + c4];
        uint2 ve = hs[(size_t)ee * 4 + c4], vf = hs[(size_t)ef * 4 + c4];
        ACC(a0, v0); ACC(a1, v1); ACC(a2, v2); ACC(a3, v3);
        ACC(a0, v4); ACC(a1, v5); ACC(a2, v6); ACC(a3, v7);
        ACC(a0, v8); ACC(a1, v9); ACC(a2, va); ACC(a3, vb);
        ACC(a0, vc); ACC(a1, vd); ACC(a2, ve); ACC(a3, vf);
      }
      for (; j + 8 <= dn; j += 8) {
        unsigned e0 = les[lo + j],     e1 = les[lo + j + 1];
        unsigned e2 = les[lo + j + 2], e3 = les[lo + j + 3];
        unsigned e4 = les[lo + j + 4], e5 = les[lo + j + 5];
        unsigned e6 = les[lo + j + 6], e7 = les[lo + j + 7];
        uint2 v0 = hs[(size_t)e0 * 4 + c4], v1 = hs[(size_t)e1 * 4 + c4];
        uint2 v2 = hs[(size_t)e2 * 4 + c4], v3 = hs[(size_t)e3 * 4 + c4];
        uint2 v4 = hs[(size_t)e4 * 4 + c4], v5 = hs[(size_t)e5 * 4 + c4];
        uint2 v6 = hs[(size_t)e6 * 4 + c4], v7 = hs[(size_t)e7 * 4 + c4];
        ACC(a0, v0); ACC(a1, v1); ACC(a2, v2); ACC(a3, v3);
        ACC(a0, v4); ACC(a1, v5); ACC(a2, v6); ACC(a3, v7);
      }
      for (; j < dn; ++j) {
        uint2 v = hs[(size_t)les[lo + j] * 4 + c4];
        ACC(a0, v);
      }
    } else {   // fallback (never for uniform data)
      for (unsigned j = 0; j < dn; ++j) {
        uint2 v = hs[(size_t)esrc[rd.x + j] * 4 + c4];
        ACC(a0, v);
      }
    }
    float4 sf = h4f(hs[(size_t)node * 4 + c4]);
    float di = dinv[node];
    int cb = c4 * 4;
    os[nl][cb + 0] = fmaxf(di * (a0.x + a1.x + a2.x + a3.x + sf.x) + b1s[cb + 0], 0.f);
    os[nl][cb + 1] = fmaxf(di * (a0.y + a1.y + a2.y + a3.y + sf.y) + b1s[cb + 1], 0.f);
    os[nl][cb + 2] = fmaxf(di * (a0.z + a1.z + a2.z + a3.z + sf.z) + b1s[cb + 2], 0.f);
    os[nl][cb + 3] = fmaxf(di * (a0.w + a1.w + a2.w + a3.w + sf.w) + b1s[cb + 3], 0.f);
  }
  __syncthreads();
  for (int idx = t; idx < 64 * 16; idx += 256) {
    int n2 = idx >> 4, cc = idx & 15;
    int node2 = node0 + n2;
    if (node2 < N) {
      float s = 0.f;
      if (cc < N_OUT) {
#pragma unroll
        for (int k = 0; k < N_HID; ++k) s += os[n2][k] * w2s[k][cc];
        s *= dinv[node2];
      }
      hs2[(size_t)node2 * N_HID + cc] = __float2half(s);
    }
  }
}

// ------ layer2: LDS-staged esrc + 16-deep CSR gather + log_softmax ------
__global__ __launch_bounds__(256) void k_gagg2(const unsigned* __restrict__ esrc,
                                               const uint2* __restrict__ rsd,
                                               const uint2* __restrict__ hs2,
                                               const float* __restrict__ dinv,
                                               const float* __restrict__ b2,
                                               float* __restrict__ out, int N) {
  __shared__ unsigned les[ECAP];
  __shared__ float zs[64][13];
  __shared__ float ls[64];
  __shared__ float b2s[N_OUT];
  int t = threadIdx.x;
  if (t < N_OUT) b2s[t] = b2[t];
  int node0 = blockIdx.x * 64;
  int lastn = min(node0 + 63, N - 1);
  uint2 rd0 = rsd[node0];
  uint2 rdl = rsd[lastn];
  unsigned bs = rd0.x, cnt = rdl.x + rdl.y - bs;
  bool fits = (cnt <= ECAP);
  if (fits) for (unsigned i = t; i < cnt; i += 256) les[i] = esrc[bs + i];
  __syncthreads();
  int nl = t >> 2, c4 = t & 3;
  int node = node0 + nl;
  if (node < N) {
    uint2 rd = rsd[node];
    unsigned dn = rd.y;
    float4 a0 = make_float4(0.f, 0.f, 0.f, 0.f), a1 = a0, a2 = a0, a3 = a0;
    if (fits) {
      unsigned lo = rd.x - bs;
      unsigned j = 0;
      for (; j + 16 <= dn; j += 16) {
        unsigned e0 = les[lo + j],      e1 = les[lo + j + 1];
        unsigned e2 = les[lo + j + 2],  e3 = les[lo + j + 3];
        unsigned e4 = les[lo + j + 4],  e5 = les[lo + j + 5];
        unsigned e6 = les[lo + j + 6],  e7 = les[lo + j + 7];
        unsigned e8 = les[lo + j + 8],  e9 = les[lo + j + 9];
        unsigned ea = les[lo + j + 10], eb = les[lo + j + 11];
        unsigned ec = les[lo + j + 12], ed = les[lo + j + 13];
        unsigned ee = les[lo + j + 14], ef = les[lo + j + 15];
        uint2 v0 = hs2[(size_t)e0 * 4 + c4], v1 = hs2[(size_t)e1 * 4 + c4];
        uint2 v2 = hs2[(size_t)e2 * 4 + c4], v3 = hs2[(size_t)e3 * 4 + c4];
        uint2 v4 = hs2[(size_t)e4 * 4 + c4], v5 = hs2[(size_t)e5 * 4 + c4];
        uint2 v6 = hs2[(size_t)e6 * 4 + c4], v7 = hs2[(size_t)e7 * 4 + c4];
        uint2 v8 = hs2[(size_t)e8 * 4 + c4], v9 = hs2[(size_t)e9 * 4 + c4];
        uint2 va = hs2[(size_t)ea * 4 + c4], vb = hs2[(size_t)eb * 4 + c4];
        uint2 vc = hs2[(size_t)ec * 4 + c4], vd = hs2[(size_t)ed * 4 + c4];
        uint2 ve = hs2[(size_t)ee * 4 + c4], vf = hs2[(size_t)ef * 4 + c4];
        ACC(a0, v0); ACC(a1, v1); ACC(a2, v2); ACC(a3, v3);
        ACC(a0, v4); ACC(a1, v5); ACC(a2, v6); ACC(a3, v7);
        ACC(a0, v8); ACC(a1, v9); ACC(a2, va); ACC(a3, vb);
        ACC(a0, vc); ACC(a1, vd); ACC(a2, ve); ACC(a3, vf);
      }
      for (; j + 8 <= dn; j += 8) {
        unsigned e0 = les[lo + j],     e1 = les[lo + j + 1];
        unsigned e2 = les[lo + j + 2], e3 = les[lo + j + 3];
        unsigned e4 = les[lo + j + 4], e5 = les[lo + j + 5];
        unsigned e6 = les[lo + j + 6], e7 = les[lo + j + 7];
        uint2 v0 = hs2[(size_t)e0 * 4 + c4], v1 = hs2[(size_t)e1 * 4 + c4];
        uint2 v2 = hs2[(size_t)e2 * 4 + c4], v3 = hs2[(size_t)e3 * 4 + c4];
        uint2 v4 = hs2[(size_t)e4 * 4 + c4], v5 = hs2[(size_t)e5 * 4 + c4];
        uint2 v6 = hs2[(size_t)e6 * 4 + c4], v7 = hs2[(size_t)e7 * 4 + c4];
        ACC(a0, v0); ACC(a1, v1); ACC(a2, v2); ACC(a3, v3);
        ACC(a0, v4); ACC(a1, v5); ACC(a2, v6); ACC(a3, v7);
      }
      for (; j < dn; ++j) {
        uint2 v = hs2[(size_t)les[lo + j] * 4 + c4];
        ACC(a0, v);
      }
    } else {
      for (unsigned j = 0; j < dn; ++j) {
        uint2 v = hs2[(size_t)esrc[rd.x + j] * 4 + c4];
        ACC(a0, v);
      }
    }
    if (c4 < 3) {
      float4 sf = h4f(hs2[(size_t)node * 4 + c4]);
      float di = dinv[node];
      int cb = c4 * 4;
      zs[nl][cb + 0] = di * (a0.x + a1.x + a2.x + a3.x + sf.x) + b2s[cb + 0];
      zs[nl][cb + 1] = di * (a0.y + a1.y + a2.y + a3.y + sf.y) + b2s[cb + 1];
      zs[nl][cb + 2] = di * (a0.z + a1.z + a2.z + a3.z + sf.z) + b2s[cb + 2];
      zs[nl][cb + 3] = di * (a0.w + a1.w + a2.w + a3.w + sf.w) + b2s[cb + 3];
    }
  }
  __syncthreads();
  if (t < 64) {
    int node2 = node0 + t;
    if (node2 < N) {
      float m = zs[t][0];
#pragma unroll
      for (int jj = 1; jj < N_OUT; ++jj) m = fmaxf(m, zs[t][jj]);
      float sum = 0.f;
#pragma unroll
      for (int jj = 0; jj < N_OUT; ++jj) sum += __expf(zs[t][jj] - m);
      ls[t] = m + __logf(sum);
    }
  }
  __syncthreads();
  for (int idx = t; idx < 64 * N_OUT; idx += 256) {
    int n2 = idx / N_OUT, cc = idx % N_OUT;
    int node2 = node0 + n2;
    if (node2 < N) out[(size_t)node2 * N_OUT + cc] = zs[n2][cc] - ls[n2];
  }
}

extern "C" void kernel_launch(void* const* d_in, const int* in_sizes, int n_in,
                              void* d_out, int out_size, void* d_ws, size_t ws_size,
                              hipStream_t stream) {
  const float* x  = (const float*)d_in[0];
  const int*   ei = (const int*)d_in[1];
  const float* W1 = (const float*)d_in[2];
  const float* b1 = (const float*)d_in[3];
  const float* W2 = (const float*)d_in[4];
  const float* b2 = (const float*)d_in[5];
  int N = in_sizes[0] / N_FIN;
  int E = in_sizes[1] / 2;
  const int* src = ei;
  const int* dst = ei + E;

  int NB = (N + BN - 1) / BN;            // 196 buckets of 512 nodes
  int M  = NB * NBLK;                    // fragment tables
  int chunk = (E + NBLK - 1) / NBLK;     // 3125 (<= STCAP)

  // ws: [hist M][lstart M][bucket_tot 1KB][dinv N][rsd N*8]
  //     [big: entries E (aliased later by fp16 hs + hs2)][esrc E]
  char* ws = (char*)d_ws;
  unsigned* hist       = (unsigned*)ws;  ws += (size_t)M * 4;
  unsigned* lstart     = (unsigned*)ws;  ws += (size_t)M * 4;
  unsigned* bucket_tot = (unsigned*)ws;  ws += 1024;
  float*    dinv       = (float*)ws;     ws += (size_t)N * 4;
  uint2*    rsd        = (uint2*)ws;     ws += (size_t)N * 8;
  size_t big_bytes = (size_t)E * 4;
  size_t hs_bytes  = (size_t)N * N_HID * 2 * 2;   // hs + hs2, fp16
  if (hs_bytes > big_bytes) big_bytes = hs_bytes;
  unsigned* entries = (unsigned*)ws;
  __half*   hs      = (__half*)ws;                 // aliases entries (dead after build)
  __half*   hs2     = (__half*)(ws + (size_t)N * N_HID * 2);
  ws += big_bytes;
  unsigned* esrc    = (unsigned*)ws;

  hipMemsetAsync(bucket_tot, 0, 1024, stream);
  k_binsort<<<NBLK, 256, 0, stream>>>(src, dst, hist, lstart, bucket_tot, entries, E, chunk, NB);
  k_build  <<<NB, 1024, 0, stream>>>(entries, hist, lstart, bucket_tot, rsd, dinv, esrc,
                                     N, NB, E, chunk);
  k_gemm1  <<<(N + 15) / 16, 256, 0, stream>>>(x, W1, dinv, hs, N);   // overwrites entries
  k_gagg1  <<<(N + 63) / 64, 256, 0, stream>>>(esrc, rsd, (const uint2*)hs,
                                               dinv, b1, W2, hs2, N);
  k_gagg2  <<<(N + 63) / 64, 256, 0, stream>>>(esrc, rsd, (const uint2*)hs2,
                                               dinv, b2, (float*)d_out, N);
}

// Round 16
// 125.224 us; speedup vs baseline: 1.0464x; 1.0464x over previous
//
#include <hip/hip_runtime.h>
#include <hip/hip_fp16.h>

#define N_FIN 128
#define N_HID 16
#define N_OUT 12
#define NBLK  1024        // binning blocks (entries layout: block-major chunks)
#define BN    512         // nodes per bucket (dl = dst & 511, bucket = dst >> 9)
#define STCAP 3200        // binsort LDS capacity (chunk = 3125)
#define SCAP  17152       // build LDS capacity per bucket (avg 16327, +6.5 sigma)
#define ECAP  4096        // gather LDS esrc stage (64 nodes: mean 2048, +45 sigma)

// ---------- block-local counting sort of a chunk by bucket ----------
__global__ __launch_bounds__(256) void k_binsort(const int* __restrict__ src,
                                                 const int* __restrict__ dst,
                                                 unsigned* __restrict__ hist,
                                                 unsigned* __restrict__ lstart,
                                                 unsigned* __restrict__ bucket_tot,
                                                 unsigned* __restrict__ entries,
                                                 int E, int chunk, int NB) {
  __shared__ unsigned lh[256];
  __shared__ unsigned cur[256];
  __shared__ unsigned stage[STCAP];
  __shared__ unsigned srt[STCAP];
  __shared__ unsigned char bid[STCAP];
  int t = threadIdx.x, blk = blockIdx.x;
  lh[t] = 0u;
  __syncthreads();
  int clo = blk * chunk, chi = min(E, clo + chunk), n = chi - clo;
  for (int j = clo + t; j < chi; j += 256) {
    int d = dst[j], s = src[j];
    int b = d >> 9;
    stage[j - clo] = ((unsigned)s << 9) | (unsigned)(d & (BN - 1));
    bid[j - clo] = (unsigned char)b;
    atomicAdd(&lh[b], 1u);
  }
  __syncthreads();
  unsigned v = lh[t];
  cur[t] = v;
  __syncthreads();
#pragma unroll
  for (int off = 1; off < 256; off <<= 1) {
    unsigned y = (t >= off) ? cur[t - off] : 0u;
    __syncthreads();
    cur[t] += y;
    __syncthreads();
  }
  unsigned excl = cur[t] - v;
  if (t < NB) {
    hist[(size_t)t * NBLK + blk]   = v;     // fragment length
    lstart[(size_t)t * NBLK + blk] = excl;  // fragment offset within chunk
    if (v) atomicAdd(&bucket_tot[t], v);
  }
  cur[t] = excl;
  __syncthreads();
  for (int i = t; i < n; i += 256) {
    unsigned p = atomicAdd(&cur[bid[i]], 1u);
    srt[p] = stage[i];
  }
  __syncthreads();
  for (int i = t; i < n; i += 256) entries[clo + i] = srt[i];   // coalesced
}

// ---------- fallback binary search ----------
__device__ __forceinline__ int frag_search(const unsigned* cum, unsigned i) {
  int lo = 0, hi = 1024;
  while (hi - lo > 1) { int mid = (lo + hi) >> 1; if (cum[mid] <= i) lo = mid; else hi = mid; }
  return lo;
}

// ---------- per-bucket build: inline scans + LUT-accelerated fragment search ----------
__global__ __launch_bounds__(1024) void k_build(const unsigned* __restrict__ entries,
                                                const unsigned* __restrict__ hist,
                                                const unsigned* __restrict__ lstart,
                                                const unsigned* __restrict__ bucket_tot,
                                                uint2* __restrict__ rsd,
                                                float* __restrict__ dinv,
                                                unsigned* __restrict__ esrc,
                                                int N, int NB, int E, int chunk) {
  __shared__ unsigned cum[1025];
  __shared__ unsigned lst[1024];
  __shared__ unsigned lut[1024];
  __shared__ unsigned cnt[BN];
  __shared__ unsigned cur[BN];
  __shared__ unsigned raw[SCAP];
  __shared__ unsigned srt[SCAP];
  int t = threadIdx.x, b = blockIdx.x;
  // inline exclusive scan of bucket totals (NB <= 256) -> bstart
  if (t < 256) cur[t] = (t < NB) ? bucket_tot[t] : 0u;
  __syncthreads();
#pragma unroll
  for (int off = 1; off < 256; off <<= 1) {
    unsigned y = 0;
    if (t < 256 && t >= off) y = cur[t - off];
    __syncthreads();
    if (t < 256) cur[t] += y;
    __syncthreads();
  }
  unsigned bstart = (b == 0) ? 0u : cur[b - 1];
  __syncthreads();
  // within-bucket fragment scan (1024 fragments)
  unsigned hv = hist[(size_t)b * NBLK + t];
  lst[t] = lstart[(size_t)b * NBLK + t];
  cum[t] = hv;
  __syncthreads();
#pragma unroll
  for (int off = 1; off < 1024; off <<= 1) {
    unsigned y = (t >= off) ? cum[t - off] : 0u;
    __syncthreads();
    cum[t] += y;
    __syncthreads();
  }
  unsigned incl = cum[t];
  __syncthreads();
  cum[t] = incl - hv;
  if (t == 1023) cum[1024] = incl;
  if (t < BN) cnt[t] = 0u;
  __syncthreads();
  unsigned tot = cum[1024];
  bool fits = (tot <= SCAP);
  // build slot LUT: fragment t covers query slots [ceil(lo*1024/tot), ceil(hi*1024/tot))
  if (tot) {
    unsigned lo = cum[t], hi = cum[t + 1];
    if (hi > lo) {
      unsigned k0 = (unsigned)(((unsigned long long)lo * 1024ull + tot - 1) / tot);
      unsigned k1 = (unsigned)(((unsigned long long)hi * 1024ull + tot - 1) / tot);
      if (k1 > 1024u) k1 = 1024u;
      for (unsigned k = k0; k < k1; ++k) lut[k] = (unsigned)t;
    }
  }
  __syncthreads();
  float scale = tot ? (1024.0f / (float)tot) : 0.f;
  // pass A: coalesced fragment reads via LUT search, stage raw, histogram dl
  if (fits) {
    for (unsigned i = t; i < tot; i += 1024) {
      unsigned k = (unsigned)((float)i * scale);
      if (k > 1023u) k = 1023u;
      int f = (int)lut[k];
      while (cum[f] > i) --f;
      while (cum[f + 1] <= i) ++f;
      unsigned en = entries[(size_t)f * chunk + lst[f] + (i - cum[f])];
      raw[i] = en;
      atomicAdd(&cnt[en & (BN - 1)], 1u);
    }
  } else {
    for (unsigned i = t; i < tot; i += 1024) {
      int f = frag_search(cum, i);
      unsigned en = entries[(size_t)f * chunk + lst[f] + (i - cum[f])];
      atomicAdd(&cnt[en & (BN - 1)], 1u);
    }
  }
  __syncthreads();
  unsigned v = (t < BN) ? cnt[t] : 0u;
  if (t < BN) cur[t] = v;
  __syncthreads();
#pragma unroll
  for (int off = 1; off < BN; off <<= 1) {
    unsigned y = (t < BN && t >= off) ? cur[t - off] : 0u;
    __syncthreads();
    if (t < BN) cur[t] += y;
    __syncthreads();
  }
  if (t < BN) {
    unsigned excl = cur[t] - v;
    cur[t] = fits ? excl : (bstart + excl);
    int node = b * BN + t;
    if (node < N) {
      rsd[node] = make_uint2(bstart + excl, v);
      dinv[node] = rsqrtf((float)(v + 1u));
    }
  }
  __syncthreads();
  if (fits) {
    for (unsigned i = t; i < tot; i += 1024) {
      unsigned en = raw[i];
      unsigned p = atomicAdd(&cur[en & (BN - 1)], 1u);
      srt[p] = en >> 9;
    }
    __syncthreads();
    for (unsigned i = t; i < tot; i += 1024) esrc[bstart + i] = srt[i];
  } else {   // fallback (never for uniform data): global scatter
    for (unsigned i = t; i < tot; i += 1024) {
      int f = frag_search(cum, i);
      unsigned en = entries[(size_t)f * chunk + lst[f] + (i - cum[f])];
      unsigned p = atomicAdd(&cur[en & (BN - 1)], 1u);
      esrc[p] = en >> 9;
    }
  }
}

// ---------------- hs = fp16( dinv * (x @ W1) ), x:[N,128] W1:[128,16] ----------------
__global__ __launch_bounds__(256) void k_gemm1(const float* __restrict__ x,
                                               const float* __restrict__ W1,
                                               const float* __restrict__ dinv,
                                               __half* __restrict__ hs, int N) {
  __shared__ float xs[16][132];
  __shared__ float wT[16][132];
  int t = threadIdx.x;
#pragma unroll
  for (int i = 0; i < 8; ++i) {
    int idx = t + i * 256;
    int k = idx >> 4, c = idx & 15;
    wT[c][k] = W1[idx];
  }
  int row0 = blockIdx.x * 16;
#pragma unroll
  for (int i = 0; i < 2; ++i) {
    int idx = t + i * 256;
    int r = idx >> 5, c4 = idx & 31;
    float4 v = make_float4(0.f, 0.f, 0.f, 0.f);
    if (row0 + r < N) v = *(const float4*)(x + (size_t)(row0 + r) * N_FIN + c4 * 4);
    *(float4*)&xs[r][c4 * 4] = v;
  }
  __syncthreads();
  int col = t & 15, r = t >> 4;
  float acc = 0.f;
#pragma unroll
  for (int kc = 0; kc < 32; ++kc) {
    float4 xv = *(const float4*)&xs[r][kc * 4];
    float4 wv = *(const float4*)&wT[col][kc * 4];
    acc += xv.x * wv.x + xv.y * wv.y + xv.z * wv.z + xv.w * wv.w;
  }
  int row = row0 + r;
  if (row < N) hs[(size_t)row * N_HID + col] = __float2half(dinv[row] * acc);
}

__device__ __forceinline__ float4 h4f(uint2 v) {
  __half2 h0 = *(__half2*)&v.x, h1 = *(__half2*)&v.y;
  float2 f0 = __half22float2(h0), f1 = __half22float2(h1);
  return make_float4(f0.x, f0.y, f1.x, f1.y);
}
#define ACC(a, v) { float4 f = h4f(v); a.x += f.x; a.y += f.y; a.z += f.z; a.w += f.w; }

// ------ layer1: LDS-staged esrc + CSR gather (4 lanes/node) + relu + 16x12 GEMM ------
__global__ __launch_bounds__(256) void k_gagg1(const unsigned* __restrict__ esrc,
                                               const uint2* __restrict__ rsd,
                                               const uint2* __restrict__ hs,
                                               const float* __restrict__ dinv,
                                               const float* __restrict__ b1,
                                               const float* __restrict__ W2,
                                               __half* __restrict__ hs2, int N) {
  __shared__ unsigned les[ECAP];
  __shared__ float os[64][17];
  __shared__ float w2s[N_HID][N_OUT];
  __shared__ float b1s[N_HID];
  int t = threadIdx.x;
  if (t < N_HID * N_OUT) w2s[t / N_OUT][t % N_OUT] = W2[t];
  if (t < N_HID) b1s[t] = b1[t];
  int node0 = blockIdx.x * 64;
  int lastn = min(node0 + 63, N - 1);
  uint2 rd0 = rsd[node0];
  uint2 rdl = rsd[lastn];
  unsigned bs = rd0.x, cnt = rdl.x + rdl.y - bs;
  bool fits = (cnt <= ECAP);
  if (fits) for (unsigned i = t; i < cnt; i += 256) les[i] = esrc[bs + i];
  __syncthreads();
  int nl = t >> 2, c4 = t & 3;
  int node = node0 + nl;
  if (node < N) {
    uint2 rd = rsd[node];
    unsigned dn = rd.y;
    float4 a0 = make_float4(0.f, 0.f, 0.f, 0.f), a1 = a0, a2 = a0, a3 = a0;
    if (fits) {
      unsigned lo = rd.x - bs;
      unsigned j = 0;
      for (; j + 8 <= dn; j += 8) {
        unsigned e0 = les[lo + j],     e1 = les[lo + j + 1];
        unsigned e2 = les[lo + j + 2], e3 = les[lo + j + 3];
        unsigned e4 = les[lo + j + 4], e5 = les[lo + j + 5];
        unsigned e6 = les[lo + j + 6], e7 = les[lo + j + 7];
        uint2 v0 = hs[(size_t)e0 * 4 + c4], v1 = hs[(size_t)e1 * 4 + c4];
        uint2 v2 = hs[(size_t)e2 * 4 + c4], v3 = hs[(size_t)e3 * 4 + c4];
        uint2 v4 = hs[(size_t)e4 * 4 + c4], v5 = hs[(size_t)e5 * 4 + c4];
        uint2 v6 = hs[(size_t)e6 * 4 + c4], v7 = hs[(size_t)e7 * 4 + c4];
        ACC(a0, v0); ACC(a1, v1); ACC(a2, v2); ACC(a3, v3);
        ACC(a0, v4); ACC(a1, v5); ACC(a2, v6); ACC(a3, v7);
      }
      for (; j < dn; ++j) {
        uint2 v = hs[(size_t)les[lo + j] * 4 + c4];
        ACC(a0, v);
      }
    } else {   // fallback (never for uniform data)
      for (unsigned j = 0; j < dn; ++j) {
        uint2 v = hs[(size_t)esrc[rd.x + j] * 4 + c4];
        ACC(a0, v);
      }
    }
    float4 sf = h4f(hs[(size_t)node * 4 + c4]);
    float di = dinv[node];
    int cb = c4 * 4;
    os[nl][cb + 0] = fmaxf(di * (a0.x + a1.x + a2.x + a3.x + sf.x) + b1s[cb + 0], 0.f);
    os[nl][cb + 1] = fmaxf(di * (a0.y + a1.y + a2.y + a3.y + sf.y) + b1s[cb + 1], 0.f);
    os[nl][cb + 2] = fmaxf(di * (a0.z + a1.z + a2.z + a3.z + sf.z) + b1s[cb + 2], 0.f);
    os[nl][cb + 3] = fmaxf(di * (a0.w + a1.w + a2.w + a3.w + sf.w) + b1s[cb + 3], 0.f);
  }
  __syncthreads();
  for (int idx = t; idx < 64 * 16; idx += 256) {
    int n2 = idx >> 4, cc = idx & 15;
    int node2 = node0 + n2;
    if (node2 < N) {
      float s = 0.f;
      if (cc < N_OUT) {
#pragma unroll
        for (int k = 0; k < N_HID; ++k) s += os[n2][k] * w2s[k][cc];
        s *= dinv[node2];
      }
      hs2[(size_t)node2 * N_HID + cc] = __float2half(s);
    }
  }
}

// ------ layer2: LDS-staged esrc + CSR gather + log_softmax ------
__global__ __launch_bounds__(256) void k_gagg2(const unsigned* __restrict__ esrc,
                                               const uint2* __restrict__ rsd,
                                               const uint2* __restrict__ hs2,
                                               const float* __restrict__ dinv,
                                               const float* __restrict__ b2,
                                               float* __restrict__ out, int N) {
  __shared__ unsigned les[ECAP];
  __shared__ float zs[64][13];
  __shared__ float ls[64];
  __shared__ float b2s[N_OUT];
  int t = threadIdx.x;
  if (t < N_OUT) b2s[t] = b2[t];
  int node0 = blockIdx.x * 64;
  int lastn = min(node0 + 63, N - 1);
  uint2 rd0 = rsd[node0];
  uint2 rdl = rsd[lastn];
  unsigned bs = rd0.x, cnt = rdl.x + rdl.y - bs;
  bool fits = (cnt <= ECAP);
  if (fits) for (unsigned i = t; i < cnt; i += 256) les[i] = esrc[bs + i];
  __syncthreads();
  int nl = t >> 2, c4 = t & 3;
  int node = node0 + nl;
  if (node < N) {
    uint2 rd = rsd[node];
    unsigned dn = rd.y;
    float4 a0 = make_float4(0.f, 0.f, 0.f, 0.f), a1 = a0, a2 = a0, a3 = a0;
    if (fits) {
      unsigned lo = rd.x - bs;
      unsigned j = 0;
      for (; j + 8 <= dn; j += 8) {
        unsigned e0 = les[lo + j],     e1 = les[lo + j + 1];
        unsigned e2 = les[lo + j + 2], e3 = les[lo + j + 3];
        unsigned e4 = les[lo + j + 4], e5 = les[lo + j + 5];
        unsigned e6 = les[lo + j + 6], e7 = les[lo + j + 7];
        uint2 v0 = hs2[(size_t)e0 * 4 + c4], v1 = hs2[(size_t)e1 * 4 + c4];
        uint2 v2 = hs2[(size_t)e2 * 4 + c4], v3 = hs2[(size_t)e3 * 4 + c4];
        uint2 v4 = hs2[(size_t)e4 * 4 + c4], v5 = hs2[(size_t)e5 * 4 + c4];
        uint2 v6 = hs2[(size_t)e6 * 4 + c4], v7 = hs2[(size_t)e7 * 4 + c4];
        ACC(a0, v0); ACC(a1, v1); ACC(a2, v2); ACC(a3, v3);
        ACC(a0, v4); ACC(a1, v5); ACC(a2, v6); ACC(a3, v7);
      }
      for (; j < dn; ++j) {
        uint2 v = hs2[(size_t)les[lo + j] * 4 + c4];
        ACC(a0, v);
      }
    } else {
      for (unsigned j = 0; j < dn; ++j) {
        uint2 v = hs2[(size_t)esrc[rd.x + j] * 4 + c4];
        ACC(a0, v);
      }
    }
    if (c4 < 3) {
      float4 sf = h4f(hs2[(size_t)node * 4 + c4]);
      float di = dinv[node];
      int cb = c4 * 4;
      zs[nl][cb + 0] = di * (a0.x + a1.x + a2.x + a3.x + sf.x) + b2s[cb + 0];
      zs[nl][cb + 1] = di * (a0.y + a1.y + a2.y + a3.y + sf.y) + b2s[cb + 1];
      zs[nl][cb + 2] = di * (a0.z + a1.z + a2.z + a3.z + sf.z) + b2s[cb + 2];
      zs[nl][cb + 3] = di * (a0.w + a1.w + a2.w + a3.w + sf.w) + b2s[cb + 3];
    }
  }
  __syncthreads();
  if (t < 64) {
    int node2 = node0 + t;
    if (node2 < N) {
      float m = zs[t][0];
#pragma unroll
      for (int jj = 1; jj < N_OUT; ++jj) m = fmaxf(m, zs[t][jj]);
      float sum = 0.f;
#pragma unroll
      for (int jj = 0; jj < N_OUT; ++jj) sum += __expf(zs[t][jj] - m);
      ls[t] = m + __logf(sum);
    }
  }
  __syncthreads();
  for (int idx = t; idx < 64 * N_OUT; idx += 256) {
    int n2 = idx / N_OUT, cc = idx % N_OUT;
    int node2 = node0 + n2;
    if (node2 < N) out[(size_t)node2 * N_OUT + cc] = zs[n2][cc] - ls[n2];
  }
}

extern "C" void kernel_launch(void* const* d_in, const int* in_sizes, int n_in,
                              void* d_out, int out_size, void* d_ws, size_t ws_size,
                              hipStream_t stream) {
  const float* x  = (const float*)d_in[0];
  const int*   ei = (const int*)d_in[1];
  const float* W1 = (const float*)d_in[2];
  const float* b1 = (const float*)d_in[3];
  const float* W2 = (const float*)d_in[4];
  const float* b2 = (const float*)d_in[5];
  int N = in_sizes[0] / N_FIN;
  int E = in_sizes[1] / 2;
  const int* src = ei;
  const int* dst = ei + E;

  int NB = (N + BN - 1) / BN;            // 196 buckets of 512 nodes
  int M  = NB * NBLK;                    // fragment tables
  int chunk = (E + NBLK - 1) / NBLK;     // 3125 (<= STCAP)

  // ws: [hist M][lstart M][bucket_tot 1KB][dinv N][rsd N*8]
  //     [big: entries E (aliased later by fp16 hs + hs2)][esrc E]
  char* ws = (char*)d_ws;
  unsigned* hist       = (unsigned*)ws;  ws += (size_t)M * 4;
  unsigned* lstart     = (unsigned*)ws;  ws += (size_t)M * 4;
  unsigned* bucket_tot = (unsigned*)ws;  ws += 1024;
  float*    dinv       = (float*)ws;     ws += (size_t)N * 4;
  uint2*    rsd        = (uint2*)ws;     ws += (size_t)N * 8;
  size_t big_bytes = (size_t)E * 4;
  size_t hs_bytes  = (size_t)N * N_HID * 2 * 2;   // hs + hs2, fp16
  if (hs_bytes > big_bytes) big_bytes = hs_bytes;
  unsigned* entries = (unsigned*)ws;
  __half*   hs      = (__half*)ws;                 // aliases entries (dead after build)
  __half*   hs2     = (__half*)(ws + (size_t)N * N_HID * 2);
  ws += big_bytes;
  unsigned* esrc    = (unsigned*)ws;

  hipMemsetAsync(bucket_tot, 0, 1024, stream);
  k_binsort<<<NBLK, 256, 0, stream>>>(src, dst, hist, lstart, bucket_tot, entries, E, chunk, NB);
  k_build  <<<NB, 1024, 0, stream>>>(entries, hist, lstart, bucket_tot, rsd, dinv, esrc,
                                     N, NB, E, chunk);
  k_gemm1  <<<(N + 15) / 16, 256, 0, stream>>>(x, W1, dinv, hs, N);   // overwrites entries
  k_gagg1  <<<(N + 63) / 64, 256, 0, stream>>>(esrc, rsd, (const uint2*)hs,
                                               dinv, b1, W2, hs2, N);
  k_gagg2  <<<(N + 63) / 64, 256, 0, stream>>>(esrc, rsd, (const uint2*)hs2,
                                               dinv, b2, (float*)d_out, N);
}